// Round 1
// 877.708 us; speedup vs baseline: 1.0620x; 1.0620x over previous
//
#include <hip/hip_runtime.h>
#include <hip/hip_bf16.h>
#include <stdint.h>

#define DIM   2048
#define NEXP  16
#define TOPK  2
#define NTOK  2048
#define NSLOT (NTOK*TOPK)   // 4096

typedef __bf16 bf16_t;
typedef __attribute__((ext_vector_type(4))) __bf16 bf16x4;
typedef __attribute__((ext_vector_type(8))) __bf16 bf16x8;
typedef __attribute__((ext_vector_type(4))) float f32x4;

// ---------------- workspace layout (bytes) ----------------
#define WS_COUNTS    1024     // int[16]
#define WS_OFFS      1152     // int[17]
#define WS_TOK_TOP   4096     // int[4096]   expert id per (token,k)
#define WS_TOK_GATE  20480    // float[4096] gate weight per (token,k)
#define WS_SLOT_TOK  36864    // int[4096]   token id per compacted slot
#define WS_SLOT_GATE 53248    // float[4096]
#define WS_IMPP      69632    // float[2048*16] per-token softmax probs (128 KB)
#define WS_XBF       262144   // bf16[NTOK*DIM]   8 MB
#define WS_H         (WS_XBF + NTOK*DIM*2)  // bf16[NSLOT*DIM] 16 MB

// ---------------- gating: one wave per token; also emits xbf (fused convert) ----------------
__global__ __launch_bounds__(256) void k_gate(const float* __restrict__ x,
                                              const float* __restrict__ Wg,
                                              const float* __restrict__ bg,
                                              float* __restrict__ imp_partial,
                                              int* __restrict__ tok_top,
                                              float* __restrict__ tok_gate,
                                              bf16_t* __restrict__ xb) {
    const int tok  = blockIdx.x * 4 + (threadIdx.x >> 6);
    const int lane = threadIdx.x & 63;
    const float* xr = x + (size_t)tok * DIM;
    bf16_t* xbr = xb + (size_t)tok * DIM;

    float acc[NEXP];
#pragma unroll
    for (int e = 0; e < NEXP; e++) acc[e] = 0.f;

#pragma unroll
    for (int i = 0; i < 8; i++) {
        int d = (i * 64 + lane) * 4;                       // 4 consecutive rows of Wg
        float4 xv = *reinterpret_cast<const float4*>(xr + d);
        // fused x -> bf16 conversion
        bf16x4 o;
        o[0] = (bf16_t)xv.x; o[1] = (bf16_t)xv.y; o[2] = (bf16_t)xv.z; o[3] = (bf16_t)xv.w;
        *reinterpret_cast<bf16x4*>(xbr + d) = o;
        const float4* wr = reinterpret_cast<const float4*>(Wg + (size_t)d * NEXP);
#pragma unroll
        for (int c = 0; c < 4; c++) {
            float xc = (&xv.x)[c];
#pragma unroll
            for (int j = 0; j < 4; j++) {
                float4 w = wr[c * 4 + j];
                acc[j * 4 + 0] += xc * w.x;
                acc[j * 4 + 1] += xc * w.y;
                acc[j * 4 + 2] += xc * w.z;
                acc[j * 4 + 3] += xc * w.w;
            }
        }
    }
#pragma unroll
    for (int e = 0; e < NEXP; e++) {
#pragma unroll
        for (int off = 32; off > 0; off >>= 1) acc[e] += __shfl_xor(acc[e], off, 64);
    }

    if (lane == 0) {
        float sc[NEXP];
#pragma unroll
        for (int e = 0; e < NEXP; e++) sc[e] = acc[e] + bg[e];
        float mx = sc[0];
#pragma unroll
        for (int e = 1; e < NEXP; e++) mx = fmaxf(mx, sc[e]);
        float p[NEXP], sum = 0.f;
#pragma unroll
        for (int e = 0; e < NEXP; e++) { p[e] = expf(sc[e] - mx); sum += p[e]; }
        float inv = 1.f / sum;
#pragma unroll
        for (int e = 0; e < NEXP; e++) imp_partial[tok * NEXP + e] = p[e] * inv;
        int i0 = 0;
#pragma unroll
        for (int e = 1; e < NEXP; e++) if (sc[e] > sc[i0]) i0 = e;
        int i1 = -1;
#pragma unroll
        for (int e = 0; e < NEXP; e++)
            if (e != i0 && (i1 < 0 || sc[e] > sc[i1])) i1 = e;
        float g0 = 1.f / (1.f + expf(sc[i1] - sc[i0]));
        tok_top[tok * 2 + 0] = i0; tok_top[tok * 2 + 1] = i1;
        tok_gate[tok * 2 + 0] = g0; tok_gate[tok * 2 + 1] = 1.f - g0;
    }
}

// ---------------- finalize: counts + offsets + aux losses + compaction (fused scatter) ----------------
__global__ __launch_bounds__(256) void k_finalize(const float* __restrict__ imp_partial,
                                                  const int* __restrict__ tok_top,
                                                  const float* __restrict__ tok_gate,
                                                  int* __restrict__ counts,
                                                  int* __restrict__ offs,
                                                  int* __restrict__ slot_tok,
                                                  float* __restrict__ slot_gate,
                                                  float* __restrict__ losses) {
    __shared__ int   scnt[NEXP];
    __shared__ int   soff[NEXP];
    __shared__ int   scur[NEXP];
    __shared__ float ired[16][NEXP + 1];
    const int t = threadIdx.x;
    if (t < NEXP) { scnt[t] = 0; scur[t] = 0; }
    __syncthreads();
    for (int i = t; i < NSLOT; i += 256) atomicAdd(&scnt[tok_top[i]], 1);
    {
        const int e = t & 15, ch = t >> 4;
        float s = 0.f;
        for (int r = ch * 128; r < ch * 128 + 128; r++) s += imp_partial[r * NEXP + e];
        ired[ch][e] = s;
    }
    __syncthreads();
    if (t == 0) {
        int o = 0;
        float cntf[NEXP];
        for (int e = 0; e < NEXP; e++) {
            counts[e] = scnt[e]; soff[e] = o; offs[e] = o; o += scnt[e]; cntf[e] = (float)scnt[e];
        }
        offs[NEXP] = o;
        float m = (float)o / NEXP, v = 0.f;
        for (int e = 0; e < NEXP; e++) { float d = cntf[e] - m; v += d * d; }
        losses[0] = (v / (NEXP - 1)) / (float)NTOK;
        float imp[NEXP];
        for (int e = 0; e < NEXP; e++) {
            float s = 0.f;
            for (int ch = 0; ch < 16; ch++) s += ired[ch][e];
            imp[e] = s;
        }
        float ms = 0.f;
        for (int e = 0; e < NEXP; e++) ms += imp[e];
        ms /= NEXP;
        float vv = 0.f;
        for (int e = 0; e < NEXP; e++) { float d = imp[e] - ms; vv += d * d; }
        losses[1] = (vv / (NEXP - 1)) / (ms + 1e-8f);
    }
    __syncthreads();
    for (int i = t; i < NSLOT; i += 256) {
        int e = tok_top[i];
        int pos = atomicAdd(&scur[e], 1);
        int slot = soff[e] + pos;
        slot_tok[slot] = i >> 1;
        slot_gate[slot] = tok_gate[i];
    }
}

// ---------------- grouped GEMM, double-buffered single-barrier pipeline ----------------
// PHASE 1: H[slot] = relu(Xbf[token(slot)] @ W1_e + b1_e)   (bf16 out)
// PHASE 2: out[token] += gate * (H[slot] @ W2_e + b2_e)     (f32 atomics)
#define BM 256
#define BN 64
#define BK 32
#define NSTEPS (DIM/BK)   // 64
#define APITCH 32   // bf16 elems per A row (64B rows, chunk-XOR-swizzled)
#define BPITCH 40   // bf16 elems per B row (80B rows)

template <int PHASE>
__global__ __launch_bounds__(512, 6) void k_gemm(const float* __restrict__ Wall,
                                                 const float* __restrict__ bias,
                                                 const bf16_t* __restrict__ Asrc,
                                                 const int* __restrict__ counts,
                                                 const int* __restrict__ offs,
                                                 const int* __restrict__ slot_tok,
                                                 const float* __restrict__ slot_gate,
                                                 bf16_t* __restrict__ Hout,
                                                 float* __restrict__ out) {
    const int e  = blockIdx.z;
    const int n0 = blockIdx.x * BN;
    const int m0 = blockIdx.y * BM;
    const int cnt = counts[e];
    if (m0 >= cnt) return;
    const int off = offs[e];

    __shared__ bf16_t As[2][BM * APITCH];   // 2 x 16 KB
    __shared__ bf16_t Bs[2][BN * BPITCH];   // 2 x  5 KB   (43 KB total -> 3 blocks/CU)

    const int tid  = threadIdx.x;
    const int lane = tid & 63, wv = tid >> 6;    // 8 waves
    const int wm = wv & 3, wn = wv >> 2;         // 4 (M) x 2 (N) wave grid; wave tile 64x32
    const int l15 = lane & 15, q = lane >> 4;

    // A staging: wave wv stages rows [wv*32, wv*32+32); LDS dest linear,
    // global source chunk pre-swizzled by key(row) = (row>>1)&3  (== (lane>>3)&3 here)
    const bf16_t* arow[2];
#pragma unroll
    for (int i = 0; i < 2; i++) {
        int rl = wv * 32 + i * 16 + (lane >> 2);
        int slot = off + m0 + rl;
        slot = slot < (NSLOT - 1) ? slot : (NSLOT - 1);   // clamp (dummy rows)
        int srow = (PHASE == 1) ? slot_tok[slot] : slot;
        int gchunk = (lane & 3) ^ ((lane >> 3) & 3);
        arow[i] = Asrc + (size_t)srow * DIM + gchunk * 8;
    }
    // B staging: wave wv (=kh) handles k-rows [kh*4, kh*4+4), col n = lane
    const int bn = tid & 63, kh = tid >> 6;
    const float* bsrc = Wall + (size_t)e * DIM * DIM + (size_t)(kh * 4) * DIM + n0 + bn;
    bf16_t* bdst0 = &Bs[0][bn * BPITCH + kh * 4];
    bf16_t* bdst1 = &Bs[1][bn * BPITCH + kh * 4];

    f32x4 acc[4][2] = {};
    float bv[4];

    // ---- prologue: stage step 0 into buf 0 ----
#pragma unroll
    for (int i = 0; i < 2; i++) {
        bf16_t* ldst = &As[0][(wv * 32 + i * 16) * APITCH];
        __builtin_amdgcn_global_load_lds(
            (const __attribute__((address_space(1))) uint32_t*)(arow[i]),
            (__attribute__((address_space(3))) uint32_t*)ldst, 16, 0, 0);
    }
#pragma unroll
    for (int kk = 0; kk < 4; kk++) bv[kk] = bsrc[(size_t)kk * DIM];
    {
        bf16x4 pk;
#pragma unroll
        for (int kk = 0; kk < 4; kk++) pk[kk] = (bf16_t)bv[kk];
        *reinterpret_cast<bf16x4*>(bdst0) = pk;
    }
    __syncthreads();

    const int akey = (l15 >> 1) & 3;

    for (int t = 0; t < NSTEPS; t++) {
        const int cur = t & 1;
        const int k1 = (t + 1) * BK;
        // ---- stage issue for step t+1 (other buffer) ----
        if (t + 1 < NSTEPS) {
#pragma unroll
            for (int i = 0; i < 2; i++) {
                bf16_t* ldst = &As[cur ^ 1][(wv * 32 + i * 16) * APITCH];
                __builtin_amdgcn_global_load_lds(
                    (const __attribute__((address_space(1))) uint32_t*)(arow[i] + k1),
                    (__attribute__((address_space(3))) uint32_t*)ldst, 16, 0, 0);
            }
            const float* bs = bsrc + (size_t)k1 * DIM;
#pragma unroll
            for (int kk = 0; kk < 4; kk++) bv[kk] = bs[(size_t)kk * DIM];
        }
        // ---- compute from buf cur ----
        bf16x8 af[4], bfr[2];
#pragma unroll
        for (int mf = 0; mf < 4; mf++)
            af[mf] = *reinterpret_cast<const bf16x8*>(
                &As[cur][(wm * 64 + mf * 16 + l15) * APITCH + ((q ^ akey) * 8)]);
#pragma unroll
        for (int nf = 0; nf < 2; nf++)
            bfr[nf] = *reinterpret_cast<const bf16x8*>(
                &Bs[cur][(wn * 32 + nf * 16 + l15) * BPITCH + q * 8]);
#pragma unroll
        for (int mf = 0; mf < 4; mf++)
#pragma unroll
            for (int nf = 0; nf < 2; nf++)
                acc[mf][nf] = __builtin_amdgcn_mfma_f32_16x16x32_bf16(af[mf], bfr[nf], acc[mf][nf], 0, 0, 0);
        // ---- commit B for step t+1 ----
        if (t + 1 < NSTEPS) {
            bf16x4 pk;
#pragma unroll
            for (int kk = 0; kk < 4; kk++) pk[kk] = (bf16_t)bv[kk];
            *reinterpret_cast<bf16x4*>((cur ^ 1) ? bdst1 : bdst0) = pk;
        }
        __syncthreads();
    }

    // epilogue; C/D layout: col = l15, row = q*4 + reg
    const int rows_here = cnt - m0;
#pragma unroll
    for (int mf = 0; mf < 4; mf++) {
#pragma unroll
        for (int r = 0; r < 4; r++) {
            int rl = wm * 64 + mf * 16 + q * 4 + r;
            if (rl >= rows_here) continue;
            int slot = off + m0 + rl;
            if (PHASE == 1) {
#pragma unroll
                for (int nf = 0; nf < 2; nf++) {
                    int col = n0 + wn * 32 + nf * 16 + l15;
                    float h = acc[mf][nf][r] + bias[e * DIM + col];
                    h = fmaxf(h, 0.f);
                    Hout[(size_t)slot * DIM + col] = (bf16_t)h;
                }
            } else {
                float g = slot_gate[slot];
                int tok = slot_tok[slot];
#pragma unroll
                for (int nf = 0; nf < 2; nf++) {
                    int col = n0 + wn * 32 + nf * 16 + l15;
                    float y = acc[mf][nf][r] + bias[e * DIM + col];
                    atomicAdd(&out[(size_t)tok * DIM + col], g * y);
                }
            }
        }
    }
}

// ---------------- launcher ----------------
extern "C" void kernel_launch(void* const* d_in, const int* in_sizes, int n_in,
                              void* d_out, int out_size, void* d_ws, size_t ws_size,
                              hipStream_t stream) {
    const float* x  = (const float*)d_in[0];
    const float* W1 = (const float*)d_in[1];
    const float* b1 = (const float*)d_in[2];
    const float* W2 = (const float*)d_in[3];
    const float* b2 = (const float*)d_in[4];
    const float* Wg = (const float*)d_in[5];
    const float* bg = (const float*)d_in[6];
    float* out = (float*)d_out;
    char*  ws  = (char*)d_ws;

    int*    counts    = (int*)(ws + WS_COUNTS);
    int*    offs      = (int*)(ws + WS_OFFS);
    int*    tok_top   = (int*)(ws + WS_TOK_TOP);
    float*  tok_gate  = (float*)(ws + WS_TOK_GATE);
    int*    slot_tok  = (int*)(ws + WS_SLOT_TOK);
    float*  slot_gate = (float*)(ws + WS_SLOT_GATE);
    float*  imp_part  = (float*)(ws + WS_IMPP);
    bf16_t* xbf       = (bf16_t*)(ws + WS_XBF);
    bf16_t* H         = (bf16_t*)(ws + WS_H);

    hipMemsetAsync(out, 0, (size_t)NTOK * DIM * sizeof(float), stream);   // out accum

    k_gate<<<NTOK / 4, 256, 0, stream>>>(x, Wg, bg, imp_part, tok_top, tok_gate, xbf);
    k_finalize<<<1, 256, 0, stream>>>(imp_part, tok_top, tok_gate, counts, offs,
                                      slot_tok, slot_gate, out + (size_t)NTOK * DIM);

    dim3 grid(DIM / BN, NTOK / BM, NEXP);  // 32 x 8 x 16; dead chunks exit early
    k_gemm<1><<<grid, 512, 0, stream>>>(W1, b1, xbf, counts, offs, slot_tok, slot_gate, H, nullptr);
    k_gemm<2><<<grid, 512, 0, stream>>>(W2, b2, H, counts, offs, slot_tok, slot_gate, nullptr, out);
}

// Round 2
// 825.390 us; speedup vs baseline: 1.1294x; 1.0634x over previous
//
#include <hip/hip_runtime.h>
#include <hip/hip_bf16.h>
#include <stdint.h>

#define DIM   2048
#define NEXP  16
#define TOPK  2
#define NTOK  2048
#define NSLOT (NTOK*TOPK)   // 4096

typedef __bf16 bf16_t;
typedef __attribute__((ext_vector_type(4))) __bf16 bf16x4;
typedef __attribute__((ext_vector_type(8))) __bf16 bf16x8;
typedef __attribute__((ext_vector_type(4))) float f32x4;

// ---------------- workspace layout (bytes) ----------------
#define WS_COUNTS    1024     // int[16]
#define WS_OFFS      1152     // int[17]
#define WS_TOK_TOP   4096     // int[4096]   expert id per (token,k)
#define WS_TOK_GATE  20480    // float[4096] gate weight per (token,k)
#define WS_SLOT_TOK  36864    // int[4096]   token id per compacted slot
#define WS_SLOT_GATE 53248    // float[4096]
#define WS_IMPP      69632    // float[2048*16] per-token softmax probs (128 KB)
#define WS_XBF       262144   // bf16[NTOK*DIM]   8 MB
#define WS_H         (WS_XBF + NTOK*DIM*2)  // bf16[NSLOT*DIM] 16 MB

// ---------------- gating: one wave per token; also emits xbf (fused convert) ----------------
__global__ __launch_bounds__(256) void k_gate(const float* __restrict__ x,
                                              const float* __restrict__ Wg,
                                              const float* __restrict__ bg,
                                              float* __restrict__ imp_partial,
                                              int* __restrict__ tok_top,
                                              float* __restrict__ tok_gate,
                                              bf16_t* __restrict__ xb) {
    const int tok  = blockIdx.x * 4 + (threadIdx.x >> 6);
    const int lane = threadIdx.x & 63;
    const float* xr = x + (size_t)tok * DIM;
    bf16_t* xbr = xb + (size_t)tok * DIM;

    float acc[NEXP];
#pragma unroll
    for (int e = 0; e < NEXP; e++) acc[e] = 0.f;

#pragma unroll
    for (int i = 0; i < 8; i++) {
        int d = (i * 64 + lane) * 4;                       // 4 consecutive rows of Wg
        float4 xv = *reinterpret_cast<const float4*>(xr + d);
        // fused x -> bf16 conversion
        bf16x4 o;
        o[0] = (bf16_t)xv.x; o[1] = (bf16_t)xv.y; o[2] = (bf16_t)xv.z; o[3] = (bf16_t)xv.w;
        *reinterpret_cast<bf16x4*>(xbr + d) = o;
        const float4* wr = reinterpret_cast<const float4*>(Wg + (size_t)d * NEXP);
#pragma unroll
        for (int c = 0; c < 4; c++) {
            float xc = (&xv.x)[c];
#pragma unroll
            for (int j = 0; j < 4; j++) {
                float4 w = wr[c * 4 + j];
                acc[j * 4 + 0] += xc * w.x;
                acc[j * 4 + 1] += xc * w.y;
                acc[j * 4 + 2] += xc * w.z;
                acc[j * 4 + 3] += xc * w.w;
            }
        }
    }
#pragma unroll
    for (int e = 0; e < NEXP; e++) {
#pragma unroll
        for (int off = 32; off > 0; off >>= 1) acc[e] += __shfl_xor(acc[e], off, 64);
    }

    if (lane == 0) {
        float sc[NEXP];
#pragma unroll
        for (int e = 0; e < NEXP; e++) sc[e] = acc[e] + bg[e];
        float mx = sc[0];
#pragma unroll
        for (int e = 1; e < NEXP; e++) mx = fmaxf(mx, sc[e]);
        float p[NEXP], sum = 0.f;
#pragma unroll
        for (int e = 0; e < NEXP; e++) { p[e] = expf(sc[e] - mx); sum += p[e]; }
        float inv = 1.f / sum;
#pragma unroll
        for (int e = 0; e < NEXP; e++) imp_partial[tok * NEXP + e] = p[e] * inv;
        int i0 = 0;
#pragma unroll
        for (int e = 1; e < NEXP; e++) if (sc[e] > sc[i0]) i0 = e;
        int i1 = -1;
#pragma unroll
        for (int e = 0; e < NEXP; e++)
            if (e != i0 && (i1 < 0 || sc[e] > sc[i1])) i1 = e;
        float g0 = 1.f / (1.f + expf(sc[i1] - sc[i0]));
        tok_top[tok * 2 + 0] = i0; tok_top[tok * 2 + 1] = i1;
        tok_gate[tok * 2 + 0] = g0; tok_gate[tok * 2 + 1] = 1.f - g0;
    }
}

// ---------------- finalize: counts + offsets + aux losses + compaction ----------------
__global__ __launch_bounds__(256) void k_finalize(const float* __restrict__ imp_partial,
                                                  const int* __restrict__ tok_top,
                                                  const float* __restrict__ tok_gate,
                                                  int* __restrict__ counts,
                                                  int* __restrict__ offs,
                                                  int* __restrict__ slot_tok,
                                                  float* __restrict__ slot_gate,
                                                  float* __restrict__ losses) {
    __shared__ int   scnt[NEXP];
    __shared__ int   soff[NEXP];
    __shared__ int   scur[NEXP];
    __shared__ float ired[16][NEXP + 1];
    const int t = threadIdx.x;
    if (t < NEXP) { scnt[t] = 0; scur[t] = 0; }
    __syncthreads();
    for (int i = t; i < NSLOT; i += 256) atomicAdd(&scnt[tok_top[i]], 1);
    {
        const int e = t & 15, ch = t >> 4;
        float s = 0.f;
        for (int r = ch * 128; r < ch * 128 + 128; r++) s += imp_partial[r * NEXP + e];
        ired[ch][e] = s;
    }
    __syncthreads();
    if (t == 0) {
        int o = 0;
        float cntf[NEXP];
        for (int e = 0; e < NEXP; e++) {
            counts[e] = scnt[e]; soff[e] = o; offs[e] = o; o += scnt[e]; cntf[e] = (float)scnt[e];
        }
        offs[NEXP] = o;
        float m = (float)o / NEXP, v = 0.f;
        for (int e = 0; e < NEXP; e++) { float d = cntf[e] - m; v += d * d; }
        losses[0] = (v / (NEXP - 1)) / (float)NTOK;
        float imp[NEXP];
        for (int e = 0; e < NEXP; e++) {
            float s = 0.f;
            for (int ch = 0; ch < 16; ch++) s += ired[ch][e];
            imp[e] = s;
        }
        float ms = 0.f;
        for (int e = 0; e < NEXP; e++) ms += imp[e];
        ms /= NEXP;
        float vv = 0.f;
        for (int e = 0; e < NEXP; e++) { float d = imp[e] - ms; vv += d * d; }
        losses[1] = (vv / (NEXP - 1)) / (ms + 1e-8f);
    }
    __syncthreads();
    for (int i = t; i < NSLOT; i += 256) {
        int e = tok_top[i];
        int pos = atomicAdd(&scur[e], 1);
        int slot = soff[e] + pos;
        slot_tok[slot] = i >> 1;
        slot_gate[slot] = tok_gate[i];
    }
}

// ---------------- grouped GEMM: counted-vmcnt deep pipeline (T3+T4+T5+T14) ----------------
// PHASE 1: H[slot] = relu(Xbf[token(slot)] @ W1_e + b1_e)   (bf16 out)
// PHASE 2: out[token] += gate * (H[slot] @ W2_e + b2_e)     (f32 atomics)
#define BM 256
#define BN 64
#define BK 32
#define NSTEPS (DIM/BK)   // 64
#define APITCH 32   // bf16 elems per A row (64B rows, chunk-XOR-swizzled)
#define BPITCH 40   // bf16 elems per B row (80B rows)

// per-wave per-iter VMEM batch = 2 gload_lds + 4 dword loads = 6; vmcnt(6) retires prev iter's batch
#define AISSUE(kidx, abuf)                                                          \
    _Pragma("unroll")                                                               \
    for (int i_ = 0; i_ < 2; i_++) {                                                \
        bf16_t* ldst_ = &(abuf)[(wv * 32 + i_ * 16) * APITCH];                      \
        __builtin_amdgcn_global_load_lds(                                           \
            (const __attribute__((address_space(1))) uint32_t*)(arow[i_] + (kidx) * BK), \
            (__attribute__((address_space(3))) uint32_t*)ldst_, 16, 0, 0);          \
    }

#define BLOAD(kidx, bv)                                                             \
    { const float* bs_ = bsrc + (size_t)((kidx) * BK) * DIM;                        \
      _Pragma("unroll")                                                             \
      for (int kk_ = 0; kk_ < 4; kk_++) (bv)[kk_] = bs_[(size_t)kk_ * DIM]; }

#define BWRITE(bv, bbuf)                                                            \
    { bf16x4 pk_;                                                                   \
      _Pragma("unroll")                                                             \
      for (int kk_ = 0; kk_ < 4; kk_++) pk_[kk_] = (bf16_t)(bv)[kk_];               \
      *reinterpret_cast<bf16x4*>(&(bbuf)[bn * BPITCH + kh * 4]) = pk_; }

#define COMPUTE(abuf, bbuf)                                                         \
    { bf16x8 af_[4], bf_[2];                                                        \
      _Pragma("unroll")                                                             \
      for (int mf_ = 0; mf_ < 4; mf_++)                                             \
          af_[mf_] = *reinterpret_cast<const bf16x8*>(                              \
              &(abuf)[(wm * 64 + mf_ * 16 + l15) * APITCH + ((q ^ akey) * 8)]);     \
      _Pragma("unroll")                                                             \
      for (int nf_ = 0; nf_ < 2; nf_++)                                             \
          bf_[nf_] = *reinterpret_cast<const bf16x8*>(                              \
              &(bbuf)[(wn * 32 + nf_ * 16 + l15) * BPITCH + q * 8]);                \
      __builtin_amdgcn_s_setprio(1);                                                \
      _Pragma("unroll")                                                             \
      for (int mf_ = 0; mf_ < 4; mf_++)                                             \
          _Pragma("unroll")                                                         \
          for (int nf_ = 0; nf_ < 2; nf_++)                                         \
              acc[mf_][nf_] = __builtin_amdgcn_mfma_f32_16x16x32_bf16(af_[mf_], bf_[nf_], acc[mf_][nf_], 0, 0, 0); \
      __builtin_amdgcn_s_setprio(0); }

#define ENDBAR()                                                                    \
    asm volatile("s_waitcnt lgkmcnt(0)" ::: "memory");                              \
    __builtin_amdgcn_s_barrier();                                                   \
    __builtin_amdgcn_sched_barrier(0);

template <int PHASE>
__global__ __launch_bounds__(512, 4) void k_gemm(const float* __restrict__ Wall,
                                                 const float* __restrict__ bias,
                                                 const bf16_t* __restrict__ Asrc,
                                                 const int* __restrict__ counts,
                                                 const int* __restrict__ offs,
                                                 const int* __restrict__ slot_tok,
                                                 const float* __restrict__ slot_gate,
                                                 bf16_t* __restrict__ Hout,
                                                 float* __restrict__ out) {
    const int e  = blockIdx.z;
    const int n0 = blockIdx.x * BN;
    const int m0 = blockIdx.y * BM;
    const int cnt = counts[e];
    if (m0 >= cnt) return;
    const int off = offs[e];

    __shared__ bf16_t As[3][BM * APITCH];   // 3 x 16 KB (rotating: compute/next/far)
    __shared__ bf16_t Bs[2][BN * BPITCH];   // 2 x  5 KB   -> 58 KB, 2 blocks/CU

    const int tid  = threadIdx.x;
    const int lane = tid & 63, wv = tid >> 6;    // 8 waves
    const int wm = wv & 3, wn = wv >> 2;         // 4 (M) x 2 (N) wave grid; wave tile 64x32
    const int l15 = lane & 15, q = lane >> 4;

    // A staging: wave wv stages rows [wv*32, wv*32+32); LDS dest linear,
    // global source chunk pre-swizzled by key(row) = (row>>1)&3
    const bf16_t* arow[2];
#pragma unroll
    for (int i = 0; i < 2; i++) {
        int rl = wv * 32 + i * 16 + (lane >> 2);
        int slot = off + m0 + rl;
        slot = slot < (NSLOT - 1) ? slot : (NSLOT - 1);   // clamp (dummy rows)
        int srow = (PHASE == 1) ? slot_tok[slot] : slot;
        int gchunk = (lane & 3) ^ ((lane >> 3) & 3);
        arow[i] = Asrc + (size_t)srow * DIM + gchunk * 8;
    }
    // B staging: wave wv (=kh) handles k-rows [kh*4, kh*4+4), col n = lane
    const int bn = tid & 63, kh = tid >> 6;
    const float* bsrc = Wall + (size_t)e * DIM * DIM + (size_t)(kh * 4) * DIM + n0 + bn;

    const int akey = (l15 >> 1) & 3;

    f32x4 acc[4][2] = {};
    float bvA[4], bvB[4];

    bf16_t* Ac = As[0];
    bf16_t* An = As[1];
    bf16_t* Af = As[2];

    // ---- prologue: A(0),B(0) then A(1),B(1); retire batch 0; commit B(0) ----
    AISSUE(0, Ac);
    BLOAD(0, bvA);
    __builtin_amdgcn_sched_barrier(0);   // pin batch-0 issue order before batch 1
    AISSUE(1, An);
    BLOAD(1, bvB);
    asm volatile("s_waitcnt vmcnt(6)" ::: "memory");   // retire A(0),B(0)
    BWRITE(bvA, Bs[0]);
    ENDBAR();

    for (int t = 0; t < NSTEPS; t += 2) {
        // ---- even iter t: compute (Ac, Bs[0]); issue A(t+2)->Af, B(t+2)->bvA; commit B(t+1)=bvB -> Bs[1]
        if (t + 2 < NSTEPS) { AISSUE(t + 2, Af); BLOAD(t + 2, bvA); }
        COMPUTE(Ac, Bs[0]);
        asm volatile("s_waitcnt vmcnt(6)" ::: "memory");   // retire prev iter's batch {A(t+1),B(t+1)}
        if (t + 1 < NSTEPS) BWRITE(bvB, Bs[1]);
        ENDBAR();
        { bf16_t* tmp = Ac; Ac = An; An = Af; Af = tmp; }

        // ---- odd iter t+1: compute (Ac, Bs[1]); issue A(t+3)->Af, B(t+3)->bvB; commit B(t+2)=bvA -> Bs[0]
        if (t + 3 < NSTEPS) { AISSUE(t + 3, Af); BLOAD(t + 3, bvB); }
        COMPUTE(Ac, Bs[1]);
        asm volatile("s_waitcnt vmcnt(6)" ::: "memory");
        if (t + 2 < NSTEPS) BWRITE(bvA, Bs[0]);
        ENDBAR();
        { bf16_t* tmp = Ac; Ac = An; An = Af; Af = tmp; }
    }

    // epilogue; C/D layout: col = l15, row = q*4 + reg
    const int rows_here = cnt - m0;
#pragma unroll
    for (int mf = 0; mf < 4; mf++) {
#pragma unroll
        for (int r = 0; r < 4; r++) {
            int rl = wm * 64 + mf * 16 + q * 4 + r;
            if (rl >= rows_here) continue;
            int slot = off + m0 + rl;
            if (PHASE == 1) {
#pragma unroll
                for (int nf = 0; nf < 2; nf++) {
                    int col = n0 + wn * 32 + nf * 16 + l15;
                    float h = acc[mf][nf][r] + bias[e * DIM + col];
                    h = fmaxf(h, 0.f);
                    Hout[(size_t)slot * DIM + col] = (bf16_t)h;
                }
            } else {
                float g = slot_gate[slot];
                int tok = slot_tok[slot];
#pragma unroll
                for (int nf = 0; nf < 2; nf++) {
                    int col = n0 + wn * 32 + nf * 16 + l15;
                    float y = acc[mf][nf][r] + bias[e * DIM + col];
                    atomicAdd(&out[(size_t)tok * DIM + col], g * y);
                }
            }
        }
    }
}

// ---------------- launcher ----------------
extern "C" void kernel_launch(void* const* d_in, const int* in_sizes, int n_in,
                              void* d_out, int out_size, void* d_ws, size_t ws_size,
                              hipStream_t stream) {
    const float* x  = (const float*)d_in[0];
    const float* W1 = (const float*)d_in[1];
    const float* b1 = (const float*)d_in[2];
    const float* W2 = (const float*)d_in[3];
    const float* b2 = (const float*)d_in[4];
    const float* Wg = (const float*)d_in[5];
    const float* bg = (const float*)d_in[6];
    float* out = (float*)d_out;
    char*  ws  = (char*)d_ws;

    int*    counts    = (int*)(ws + WS_COUNTS);
    int*    offs      = (int*)(ws + WS_OFFS);
    int*    tok_top   = (int*)(ws + WS_TOK_TOP);
    float*  tok_gate  = (float*)(ws + WS_TOK_GATE);
    int*    slot_tok  = (int*)(ws + WS_SLOT_TOK);
    float*  slot_gate = (float*)(ws + WS_SLOT_GATE);
    float*  imp_part  = (float*)(ws + WS_IMPP);
    bf16_t* xbf       = (bf16_t*)(ws + WS_XBF);
    bf16_t* H         = (bf16_t*)(ws + WS_H);

    hipMemsetAsync(out, 0, (size_t)NTOK * DIM * sizeof(float), stream);   // out accum

    k_gate<<<NTOK / 4, 256, 0, stream>>>(x, Wg, bg, imp_part, tok_top, tok_gate, xbf);
    k_finalize<<<1, 256, 0, stream>>>(imp_part, tok_top, tok_gate, counts, offs,
                                      slot_tok, slot_gate, out + (size_t)NTOK * DIM);

    dim3 grid(DIM / BN, NTOK / BM, NEXP);  // 32 x 8 x 16; dead chunks exit early
    k_gemm<1><<<grid, 512, 0, stream>>>(W1, b1, xbf, counts, offs, slot_tok, slot_gate, H, nullptr);
    k_gemm<2><<<grid, 512, 0, stream>>>(W2, b2, H, counts, offs, slot_tok, slot_gate, nullptr, out);
}

// Round 3
// 824.630 us; speedup vs baseline: 1.1304x; 1.0009x over previous
//
#include <hip/hip_runtime.h>
#include <hip/hip_bf16.h>
#include <stdint.h>

#define DIM   2048
#define NEXP  16
#define TOPK  2
#define NTOK  2048
#define NSLOT (NTOK*TOPK)   // 4096

typedef __bf16 bf16_t;
typedef __attribute__((ext_vector_type(4))) __bf16 bf16x4;
typedef __attribute__((ext_vector_type(8))) __bf16 bf16x8;
typedef __attribute__((ext_vector_type(4))) float f32x4;

// ---------------- workspace layout (bytes) ----------------
#define WS_COUNTS    1024
#define WS_OFFS      1152
#define WS_TOK_TOP   4096
#define WS_TOK_GATE  20480
#define WS_SLOT_TOK  36864
#define WS_SLOT_GATE 53248
#define WS_IMPP      69632
#define WS_XBF       262144
#define WS_H         (WS_XBF + NTOK*DIM*2)

// ---------------- gating: one wave per token; fused x->bf16; coalesced Wg ----------------
__global__ __launch_bounds__(256) void k_gate(const float* __restrict__ x,
                                              const float* __restrict__ Wg,
                                              const float* __restrict__ bg,
                                              float* __restrict__ imp_partial,
                                              int* __restrict__ tok_top,
                                              float* __restrict__ tok_gate,
                                              bf16_t* __restrict__ xb) {
    const int tok  = blockIdx.x * 4 + (threadIdx.x >> 6);
    const int lane = threadIdx.x & 63;
    const float* xr = x + (size_t)tok * DIM;
    bf16_t* xbr = xb + (size_t)tok * DIM;

    // fused x -> bf16 conversion (coalesced float4)
#pragma unroll
    for (int i = 0; i < 8; i++) {
        int d = (i * 64 + lane) * 4;
        float4 v = *reinterpret_cast<const float4*>(xr + d);
        bf16x4 o;
        o[0] = (bf16_t)v.x; o[1] = (bf16_t)v.y; o[2] = (bf16_t)v.z; o[3] = (bf16_t)v.w;
        *reinterpret_cast<bf16x4*>(xbr + d) = o;
    }

    // gate GEMV: lane owns expert group jq (4 experts), row offset ro.
    // per instruction: 64 lanes cover 16 consecutive Wg rows x all 16 experts = 1KB contiguous.
    const int jq = lane & 3, ro = lane >> 2;
    float a0 = 0.f, a1 = 0.f, a2 = 0.f, a3 = 0.f;
#pragma unroll 4
    for (int i = 0; i < 128; i++) {
        int d = i * 16 + ro;
        float xc = xr[d];
        float4 w = *reinterpret_cast<const float4*>(Wg + (size_t)d * NEXP + jq * 4);
        a0 += xc * w.x; a1 += xc * w.y; a2 += xc * w.z; a3 += xc * w.w;
    }
    // butterfly over masks 4..32 (preserves jq bits 0-1): sums all rows within each group
#pragma unroll
    for (int off = 4; off <= 32; off <<= 1) {
        a0 += __shfl_xor(a0, off, 64);
        a1 += __shfl_xor(a1, off, 64);
        a2 += __shfl_xor(a2, off, 64);
        a3 += __shfl_xor(a3, off, 64);
    }
    // gather full score vector (lane e>>2 holds group e>>2)
    float sc[NEXP];
#pragma unroll
    for (int e = 0; e < NEXP; e++) {
        float v = (e & 3) == 0 ? a0 : ((e & 3) == 1 ? a1 : ((e & 3) == 2 ? a2 : a3));
        sc[e] = __shfl(v, e >> 2, 64) + bg[e];
    }

    if (lane == 0) {
        float mx = sc[0];
#pragma unroll
        for (int e = 1; e < NEXP; e++) mx = fmaxf(mx, sc[e]);
        float p[NEXP], sum = 0.f;
#pragma unroll
        for (int e = 0; e < NEXP; e++) { p[e] = expf(sc[e] - mx); sum += p[e]; }
        float inv = 1.f / sum;
#pragma unroll
        for (int e = 0; e < NEXP; e++) imp_partial[tok * NEXP + e] = p[e] * inv;
        int i0 = 0;
#pragma unroll
        for (int e = 1; e < NEXP; e++) if (sc[e] > sc[i0]) i0 = e;
        int i1 = -1;
#pragma unroll
        for (int e = 0; e < NEXP; e++)
            if (e != i0 && (i1 < 0 || sc[e] > sc[i1])) i1 = e;
        float g0 = 1.f / (1.f + expf(sc[i1] - sc[i0]));
        tok_top[tok * 2 + 0] = i0; tok_top[tok * 2 + 1] = i1;
        tok_gate[tok * 2 + 0] = g0; tok_gate[tok * 2 + 1] = 1.f - g0;
    }
}

// ---------------- finalize: counts + offsets + aux losses + compaction ----------------
__global__ __launch_bounds__(256) void k_finalize(const float* __restrict__ imp_partial,
                                                  const int* __restrict__ tok_top,
                                                  const float* __restrict__ tok_gate,
                                                  int* __restrict__ counts,
                                                  int* __restrict__ offs,
                                                  int* __restrict__ slot_tok,
                                                  float* __restrict__ slot_gate,
                                                  float* __restrict__ losses) {
    __shared__ int   scnt[NEXP];
    __shared__ int   soff[NEXP];
    __shared__ int   scur[NEXP];
    __shared__ float ired[16][NEXP + 1];
    const int t = threadIdx.x;
    if (t < NEXP) { scnt[t] = 0; scur[t] = 0; }
    __syncthreads();
    for (int i = t; i < NSLOT; i += 256) atomicAdd(&scnt[tok_top[i]], 1);
    {
        const int e = t & 15, ch = t >> 4;
        float s = 0.f;
        for (int r = ch * 128; r < ch * 128 + 128; r++) s += imp_partial[r * NEXP + e];
        ired[ch][e] = s;
    }
    __syncthreads();
    if (t == 0) {
        int o = 0;
        float cntf[NEXP];
        for (int e = 0; e < NEXP; e++) {
            counts[e] = scnt[e]; soff[e] = o; offs[e] = o; o += scnt[e]; cntf[e] = (float)scnt[e];
        }
        offs[NEXP] = o;
        float m = (float)o / NEXP, v = 0.f;
        for (int e = 0; e < NEXP; e++) { float d = cntf[e] - m; v += d * d; }
        losses[0] = (v / (NEXP - 1)) / (float)NTOK;
        float imp[NEXP];
        for (int e = 0; e < NEXP; e++) {
            float s = 0.f;
            for (int ch = 0; ch < 16; ch++) s += ired[ch][e];
            imp[e] = s;
        }
        float ms = 0.f;
        for (int e = 0; e < NEXP; e++) ms += imp[e];
        ms /= NEXP;
        float vv = 0.f;
        for (int e = 0; e < NEXP; e++) { float d = imp[e] - ms; vv += d * d; }
        losses[1] = (vv / (NEXP - 1)) / (ms + 1e-8f);
    }
    __syncthreads();
    for (int i = t; i < NSLOT; i += 256) {
        int e = tok_top[i];
        int pos = atomicAdd(&scur[e], 1);
        int slot = soff[e] + pos;
        slot_tok[slot] = i >> 1;
        slot_gate[slot] = tok_gate[i];
    }
}

// ---------------- grouped GEMM: uniform-batch counted-vmcnt pipeline ----------------
// PHASE 1: H[slot] = relu(Xbf[token(slot)] @ W1_e + b1_e)   (bf16 out)
// PHASE 2: out[token] += gate * (H[slot] @ W2_e + b2_e)     (f32 atomics)
#define BM 256
#define BN 128
#define BK 32
#define NSTEPS (DIM/BK)   // 64
#define APITCH 32         // bf16/row (64B rows, chunk-XOR-swizzled)
#define BPITCH 40         // bf16/row (80B rows)

// batch at iter t = [A(t+2) 2 ops][B(t+3) 8 ops] = 10 VMEM ops/wave.
// single vmcnt(10) at end of iter retires batch t-1 entirely, BEFORE the barrier:
// -> A(t+1) globally visible for compute t+1, B(t+2) regs ready for cvt at t+1.

#define AISSUE(kidx, abuf)                                                          \
    _Pragma("unroll")                                                               \
    for (int i_ = 0; i_ < 2; i_++) {                                                \
        bf16_t* ldst_ = &(abuf)[(wv * 32 + i_ * 16) * APITCH];                      \
        __builtin_amdgcn_global_load_lds(                                           \
            (const __attribute__((address_space(1))) uint32_t*)(arow[i_] + (size_t)(kidx) * BK), \
            (__attribute__((address_space(3))) uint32_t*)ldst_, 16, 0, 0);          \
    }

#define BLOAD8(kidx, BV)                                                            \
    { const float* bs_ = bsrc + (size_t)(kidx) * (BK * DIM);                        \
      _Pragma("unroll")                                                             \
      for (int kk_ = 0; kk_ < 8; kk_++) (BV)[kk_] = bs_[(size_t)kk_ * DIM]; }

#define COMPUTE(abuf, bbuf)                                                         \
    { bf16x8 af_[4], bf_[4];                                                        \
      _Pragma("unroll")                                                             \
      for (int mf_ = 0; mf_ < 4; mf_++)                                             \
          af_[mf_] = *reinterpret_cast<const bf16x8*>(                              \
              &(abuf)[(wm * 64 + mf_ * 16 + l15) * APITCH + ((q ^ akey) * 8)]);     \
      _Pragma("unroll")                                                             \
      for (int nf_ = 0; nf_ < 4; nf_++)                                             \
          bf_[nf_] = *reinterpret_cast<const bf16x8*>(                              \
              &(bbuf)[(wn * 64 + nf_ * 16 + l15) * BPITCH + q * 8]);                \
      __builtin_amdgcn_s_setprio(1);                                                \
      _Pragma("unroll")                                                             \
      for (int mf_ = 0; mf_ < 4; mf_++)                                             \
          _Pragma("unroll")                                                         \
          for (int nf_ = 0; nf_ < 4; nf_++)                                         \
              acc[mf_][nf_] = __builtin_amdgcn_mfma_f32_16x16x32_bf16(af_[mf_], bf_[nf_], acc[mf_][nf_], 0, 0, 0); \
      __builtin_amdgcn_s_setprio(0); }

// one iteration: cvt+write B(t+1); issue batch [A(t+2), B(t+3)]; compute; wait batch t-1; barrier
#define GITER(BV, BSR, BSW, DO_A, DO_B, VMC)                                        \
    {                                                                               \
        bf16x8 pk_;                                                                 \
        _Pragma("unroll")                                                           \
        for (int u_ = 0; u_ < 8; u_++) pk_[u_] = (bf16_t)(BV)[u_];                  \
        if (DO_A) { AISSUE(t + 2, Af); }                                            \
        *reinterpret_cast<bf16x8*>(&(BSW)[bn * BPITCH + kq * 8]) = pk_;             \
        if (DO_B) { BLOAD8(t + 3, BV); }                                            \
        COMPUTE(Ac, BSR);                                                           \
        asm volatile("s_waitcnt vmcnt(" #VMC ")" ::: "memory");                     \
        asm volatile("s_waitcnt lgkmcnt(0)" ::: "memory");                          \
        __builtin_amdgcn_s_barrier();                                              \
        __builtin_amdgcn_sched_barrier(0);                                          \
        { bf16_t* tp_ = Ac; Ac = An; An = Af; Af = tp_; }                           \
        ++t;                                                                        \
    }

template <int PHASE>
__global__ __launch_bounds__(512, 4) void k_gemm(const float* __restrict__ Wall,
                                                 const float* __restrict__ bias,
                                                 const bf16_t* __restrict__ Asrc,
                                                 const int* __restrict__ counts,
                                                 const int* __restrict__ offs,
                                                 const int* __restrict__ slot_tok,
                                                 const float* __restrict__ slot_gate,
                                                 bf16_t* __restrict__ Hout,
                                                 float* __restrict__ out) {
    const int e  = blockIdx.z;
    const int n0 = blockIdx.x * BN;
    const int m0 = blockIdx.y * BM;
    const int cnt = counts[e];
    if (m0 >= cnt) return;
    const int off = offs[e];

    __shared__ bf16_t As[3][BM * APITCH];   // 3 x 16 KB rotating
    __shared__ bf16_t Bs[2][BN * BPITCH];   // 2 x 10 KB  -> 68 KB total, 2 blocks/CU

    const int tid  = threadIdx.x;
    const int lane = tid & 63, wv = tid >> 6;    // 8 waves
    const int wm = wv & 3, wn = wv >> 2;         // 4(M) x 2(N); wave tile 64x64
    const int l15 = lane & 15, q = lane >> 4;

    // A staging: wave wv stages rows [wv*32, wv*32+32); linear LDS dest,
    // global source chunk pre-swizzled by key(row) = (row>>1)&3
    const bf16_t* arow[2];
#pragma unroll
    for (int i = 0; i < 2; i++) {
        int rl = wv * 32 + i * 16 + (lane >> 2);
        int slot = off + m0 + rl;
        slot = slot < (NSLOT - 1) ? slot : (NSLOT - 1);   // clamp (dummy rows)
        int srow = (PHASE == 1) ? slot_tok[slot] : slot;
        int gchunk = (lane & 3) ^ ((lane >> 3) & 3);
        arow[i] = Asrc + (size_t)srow * DIM + gchunk * 8;
    }
    // B staging: thread t -> col n = t&127, k-octet kq = t>>7 (8 consecutive k)
    const int bn = tid & 127, kq = tid >> 7;
    const float* bsrc = Wall + (size_t)e * DIM * DIM + (size_t)(kq * 8) * DIM + n0 + bn;

    const int akey = (l15 >> 1) & 3;

    f32x4 acc[4][4] = {};
    float bv0[8], bv1[8], bvt[8];

    bf16_t *Ac = As[0], *An = As[1], *Af = As[2];
    int t = 0;

    // ---- prologue: queue = [B0 8][A0 2][B1 8][A1 2][B2 8]; keep newest 10 = [A1,B2] ----
    BLOAD8(0, bvt);
    __builtin_amdgcn_sched_barrier(0);
    AISSUE(0, Ac);
    __builtin_amdgcn_sched_barrier(0);
    BLOAD8(1, bv1);
    __builtin_amdgcn_sched_barrier(0);
    AISSUE(1, An);
    __builtin_amdgcn_sched_barrier(0);
    BLOAD8(2, bv0);
    asm volatile("s_waitcnt vmcnt(10)" ::: "memory");
    {
        bf16x8 pk;
#pragma unroll
        for (int u = 0; u < 8; u++) pk[u] = (bf16_t)bvt[u];
        *reinterpret_cast<bf16x8*>(&Bs[0][bn * BPITCH + kq * 8]) = pk;
    }
    asm volatile("s_waitcnt lgkmcnt(0)" ::: "memory");
    __builtin_amdgcn_s_barrier();
    __builtin_amdgcn_sched_barrier(0);

    // ---- steady: t = 0..59 (30 x 2), then t=60 (still full-issue) ----
#pragma unroll 1
    for (int o = 0; o < 30; ++o) {
        GITER(bv1, Bs[0], Bs[1], true, true, 10);
        GITER(bv0, Bs[1], Bs[0], true, true, 10);
    }
    GITER(bv1, Bs[0], Bs[1], true, true, 10);   // t=60
    // ---- tails ----
    GITER(bv0, Bs[1], Bs[0], true,  false, 2);  // t=61: issue A(63); retire A62,B63
    GITER(bv1, Bs[0], Bs[1], false, false, 0);  // t=62: retire A63
    COMPUTE(Ac, Bs[1]);                         // t=63

    // epilogue; C/D layout: col = l15, row = q*4 + reg
    const int rows_here = cnt - m0;
#pragma unroll
    for (int mf = 0; mf < 4; mf++) {
#pragma unroll
        for (int r = 0; r < 4; r++) {
            int rl = wm * 64 + mf * 16 + q * 4 + r;
            if (rl >= rows_here) continue;
            int slot = off + m0 + rl;
            if (PHASE == 1) {
#pragma unroll
                for (int nf = 0; nf < 4; nf++) {
                    int col = n0 + wn * 64 + nf * 16 + l15;
                    float h = acc[mf][nf][r] + bias[e * DIM + col];
                    h = fmaxf(h, 0.f);
                    Hout[(size_t)slot * DIM + col] = (bf16_t)h;
                }
            } else {
                float g = slot_gate[slot];
                int tok = slot_tok[slot];
#pragma unroll
                for (int nf = 0; nf < 4; nf++) {
                    int col = n0 + wn * 64 + nf * 16 + l15;
                    float y = acc[mf][nf][r] + bias[e * DIM + col];
                    atomicAdd(&out[(size_t)tok * DIM + col], g * y);
                }
            }
        }
    }
}

// ---------------- launcher ----------------
extern "C" void kernel_launch(void* const* d_in, const int* in_sizes, int n_in,
                              void* d_out, int out_size, void* d_ws, size_t ws_size,
                              hipStream_t stream) {
    const float* x  = (const float*)d_in[0];
    const float* W1 = (const float*)d_in[1];
    const float* b1 = (const float*)d_in[2];
    const float* W2 = (const float*)d_in[3];
    const float* b2 = (const float*)d_in[4];
    const float* Wg = (const float*)d_in[5];
    const float* bg = (const float*)d_in[6];
    float* out = (float*)d_out;
    char*  ws  = (char*)d_ws;

    int*    counts    = (int*)(ws + WS_COUNTS);
    int*    offs      = (int*)(ws + WS_OFFS);
    int*    tok_top   = (int*)(ws + WS_TOK_TOP);
    float*  tok_gate  = (float*)(ws + WS_TOK_GATE);
    int*    slot_tok  = (int*)(ws + WS_SLOT_TOK);
    float*  slot_gate = (float*)(ws + WS_SLOT_GATE);
    float*  imp_part  = (float*)(ws + WS_IMPP);
    bf16_t* xbf       = (bf16_t*)(ws + WS_XBF);
    bf16_t* H         = (bf16_t*)(ws + WS_H);

    hipMemsetAsync(out, 0, (size_t)NTOK * DIM * sizeof(float), stream);

    k_gate<<<NTOK / 4, 256, 0, stream>>>(x, Wg, bg, imp_part, tok_top, tok_gate, xbf);
    k_finalize<<<1, 256, 0, stream>>>(imp_part, tok_top, tok_gate, counts, offs,
                                      slot_tok, slot_gate, out + (size_t)NTOK * DIM);

    dim3 grid(DIM / BN, 4, NEXP);  // 16 x 4 x 16; dead chunks exit early (cnt<=1024 covered)
    k_gemm<1><<<grid, 512, 0, stream>>>(W1, b1, xbf, counts, offs, slot_tok, slot_gate, H, nullptr);
    k_gemm<2><<<grid, 512, 0, stream>>>(W2, b2, H, counts, offs, slot_tok, slot_gate, nullptr, out);
}